// Round 12
// baseline (37.366 us; speedup 1.0000x reference)
//
#include <hip/hip_runtime.h>
#include <math.h>

namespace {

constexpr int K = 256, D = 256, P = 40, C = 32;
constexpr int LN = 2048;     // LUT intervals over s in [-1,1]
constexpr int NOUT = K * K;  // 65536
constexpr int LB = (LN + 1 + 255) / 256;  // LUT blocks
constexpr int NCH = 8, PPC = 5;           // 8 p-chunks x 5 p, one chunk per XCD

typedef __attribute__((ext_vector_type(8))) short bf16x8;
typedef __attribute__((ext_vector_type(4))) float f32x4;

__device__ __forceinline__ float tanh_fast(float x) {
  float e = __expf(2.0f * x);
  return 1.0f - __fdividef(2.0f, e + 1.0f);
}

// round-to-nearest bf16 split: (hi16) | (lo16 << 16); hi+lo ~ v to ~2^-18 rel
__device__ __forceinline__ unsigned bf16pair(float v) {
  unsigned u = __float_as_uint(v);
  unsigned hi = (u + 0x7fffu + ((u >> 16) & 1u)) >> 16;
  float lo = v - __uint_as_float(hi << 16);
  unsigned ul = __float_as_uint(lo);
  unsigned lo16 = (ul + 0x7fffu + ((ul >> 16) & 1u)) >> 16;
  return hi | (lo16 << 16);
}

__device__ __forceinline__ void gload16(const void* g, void* l) {
  __builtin_amdgcn_global_load_lds((const __attribute__((address_space(1))) void*)g,
                                   (__attribute__((address_space(3))) void*)l, 16, 0, 0);
}

// ---- prep (+ merged init): blocks [0,2K): L2-norm+transpose+bf16-split;
//      then LUT blocks; then pw block ----
__global__ __launch_bounds__(256) void kprep(const float* __restrict__ e,
                                             const float* __restrict__ ts,
                                             const float* __restrict__ fc1w,
                                             const float* __restrict__ fc1b,
                                             const float* __restrict__ fc2w,
                                             const float* __restrict__ pho_w,
                                             unsigned* __restrict__ Ep,
                                             unsigned* __restrict__ Tp,
                                             float* __restrict__ tab,
                                             float* __restrict__ pwv) {
  const int bid = blockIdx.x;
  const int t = threadIdx.x;
  if (bid >= 2 * K) {
    int ib = bid - 2 * K;
    if (ib < LB) {
      int i = ib * 256 + t;
      if (i <= LN) {
        float s = -1.0f + (float)i * (2.0f / LN);
        float g = 0.f;
#pragma unroll
        for (int c = 0; c < C; ++c) g = fmaf(tanh_fast(fmaf(s, fc1w[c], fc1b[c])), fc2w[c], g);
        tab[i] = tanh_fast(g * s);
      }
      return;
    }
    // pw block: pwv[0..P) normalized weights, pwv[P] = sum
    float wmin = pho_w[0], wmax = pho_w[0];
    for (int i = 1; i < P; ++i) {
      float v = pho_w[i];
      wmin = fminf(wmin, v);
      wmax = fmaxf(wmax, v);
    }
    float inv = 1.0f / (1e-6f + wmax - wmin);
    if (t < P) pwv[t] = (pho_w[t] - wmin) * inv;
    if (t == 64) {
      float sum = 0.f;
      for (int i = 0; i < P; ++i) sum += (pho_w[i] - wmin) * inv;
      pwv[P] = sum;
    }
    return;
  }
  // ---- prep path ----
  __shared__ float tile[D * 41];  // padded stride 41
  __shared__ float red[240];
  __shared__ float inv[P];
  const float* x = (bid < K) ? e : ts;
  unsigned* xt = (bid < K) ? Ep : Tp;
  const int a = bid & (K - 1);
  const float4* src4 = (const float4*)(x + (size_t)a * D * P);
#pragma unroll
  for (int i4 = t; i4 < (D * P) / 4; i4 += 256) {
    float4 v = src4[i4];
    int d = i4 / 10;
    int p0 = (i4 - d * 10) * 4;
    float* dst = &tile[d * 41 + p0];
    dst[0] = v.x;
    dst[1] = v.y;
    dst[2] = v.z;
    dst[3] = v.w;
  }
  __syncthreads();
  if (t < 240) {  // 6 threads per column
    int p = t / 6, j = t - (t / 6) * 6;
    float ss = 0.f;
    for (int d = j; d < D; d += 6) {
      float v = tile[d * 41 + p];
      ss = fmaf(v, v, ss);
    }
    red[t] = ss;
  }
  __syncthreads();
  if (t < P) {
    float ss = red[t * 6] + red[t * 6 + 1] + red[t * 6 + 2] + red[t * 6 + 3] +
               red[t * 6 + 4] + red[t * 6 + 5];
    inv[t] = 1.0f / fmaxf(sqrtf(ss), 1e-12f);
  }
  __syncthreads();
  for (int i = t; i < (D * P) / 2; i += 256) {
    int p = i >> 7, d = (i & 127) * 2;
    float iv = inv[p];
    unsigned u0 = bf16pair(tile[d * 41 + p] * iv);
    unsigned u1 = bf16pair(tile[(d + 1) * 41 + p] * iv);
    *(uint2*)&xt[((size_t)p * K + a) * 256 + d] = make_uint2(u0, u1);
  }
}

// ---- kgemm: 512 blocks = 64 tiles x 8 chunks; chunk c pinned to XCD c (id&7);
//      per-XCD working set 2.6 MB -> L2-resident. Register F-accum over 5 p,
//      double-buffered gload_lds (counted vmcnt), LDS LUT, non-atomic write ----
__global__ __launch_bounds__(256) void kgemm(const unsigned* __restrict__ Ep,
                                             const unsigned* __restrict__ Tp,
                                             const float* __restrict__ tab,
                                             const float* __restrict__ pwv,
                                             float* __restrict__ part,
                                             float* __restrict__ corrp) {
  __shared__ __align__(16) char Buf[2][64 * 1024];  // [buf][A 32KB | B 32KB]
  __shared__ __align__(16) float lt[LN + 4];        // 8.2 KB LUT
  // decode: id = tile*8 + chunk; round-robin dispatch puts chunk c on XCD c
  const int id = blockIdx.x;
  const int chunk = id & 7;
  const int tile = id >> 3;  // 0..63
  const int a0 = (tile >> 3) * 32, b0 = (tile & 7) * 32;
  const int p0 = chunk * PPC;
  const int t = threadIdx.x, lane = t & 63, w = t >> 6;

  // staging geometry: waves 0,1 -> A rows 0..31; waves 2,3 -> B rows 0..31
  const bool isB = (w >= 2);
  const char* gbase = isB ? (const char*)Tp : (const char*)Ep;
  const int rowbase = isB ? b0 : a0;
  const int dofs = isB ? 32 * 1024 : 0;
  const int rw = (w & 1) * 16;

  auto stage = [&](char* buf, int p) {
    const char* src = gbase + (size_t)p * (K * 1024);
    char* dst = buf + dofs;
#pragma unroll
    for (int i = 0; i < 16; ++i) {
      const int r = rw + i;
      gload16(src + (size_t)(rowbase + r) * 1024 + ((lane * 16) ^ ((r & 7) << 4)),
              dst + r * 1024);
    }
  };

  // preload pw for this chunk (keeps vmem out of the counted-vmcnt loop)
  float pwreg[PPC];
#pragma unroll
  for (int i = 0; i < PPC; ++i) pwreg[i] = pwv[p0 + i];

  stage(Buf[0], p0);  // prologue: 16 loads in flight

  {  // LUT -> LDS (8 KB)
    const float4* t4 = (const float4*)tab;
    float4* l4 = (float4*)lt;
    l4[t] = t4[t];
    l4[t + 256] = t4[t + 256];
    if (t == 0) lt[LN] = tab[LN];
  }
  asm volatile("s_waitcnt vmcnt(0) lgkmcnt(0)" ::: "memory");
  __builtin_amdgcn_s_barrier();
  __builtin_amdgcn_sched_barrier(0);

  // fragment read geometry: wave w owns 16x16 quadrant (qr, qc)
  const int qr = (w >> 1) * 16, qc = (w & 1) * 16;
  const int l15 = lane & 15, hi16 = (lane >> 4) * 16;
  const int rsw = (l15 & 7) << 4;

  float sc[4] = {0.f, 0.f, 0.f, 0.f};
  float cz[4] = {0.f, 0.f, 0.f, 0.f};

#pragma unroll
  for (int pi = 0; pi < PPC; ++pi) {
    const int cur = pi & 1;
    if (pi < PPC - 1) {
      stage(Buf[cur ^ 1], p0 + pi + 1);                  // 16 more in flight
      asm volatile("s_waitcnt vmcnt(16)" ::: "memory");  // current buf's 16 done
    } else {
      asm volatile("s_waitcnt vmcnt(0)" ::: "memory");
    }
    __builtin_amdgcn_s_barrier();
    __builtin_amdgcn_sched_barrier(0);
    const char* Ar = Buf[cur] + (size_t)(qr + l15) * 1024;
    const char* Br = Buf[cur] + 32 * 1024 + (size_t)(qc + l15) * 1024;
    f32x4 acc = {0.f, 0.f, 0.f, 0.f};
#pragma unroll
    for (int ks = 0; ks < 16; ++ks) {
      const int off = (ks * 64 + hi16) ^ rsw;
      bf16x8 af = *(const bf16x8*)(Ar + off);
      bf16x8 bf = *(const bf16x8*)(Br + off);
      acc = __builtin_amdgcn_mfma_f32_16x16x32_bf16(af, bf, acc, 0, 0, 0);
    }
    const float pwp = pwreg[pi];
#pragma unroll
    for (int j = 0; j < 4; ++j) {
      float s = acc[j];
      float u = fminf(fmaxf((s + 1.0f) * (LN / 2), 0.0f), (float)LN);
      int i = min((int)u, LN - 1);
      float F = fmaf(u - (float)i, lt[i + 1] - lt[i], lt[i]);
      sc[j] = fmaf(F, pwp, sc[j]);
      if (s == 0.0f) cz[j] += pwp;  // never taken on real data
    }
    __builtin_amdgcn_s_barrier();  // all reads of Buf[cur] done before re-stage
    __builtin_amdgcn_sched_barrier(0);
  }

  // non-atomic plane write: exactly one writer per (chunk, element)
  const int ar = a0 + qr + (lane >> 4) * 4;
  const int bc = b0 + qc + l15;
  float* pp = part + (size_t)chunk * NOUT;
  float* cp = corrp + (size_t)chunk * NOUT;
#pragma unroll
  for (int j = 0; j < 4; ++j) {
    pp[(ar + j) * K + bc] = sc[j];
    cp[(ar + j) * K + bc] = cz[j];
  }
}

// ---- finalize: reduce 8 chunk planes, divide ----
__global__ __launch_bounds__(256) void kdiv(const float* __restrict__ part,
                                            const float* __restrict__ corrp,
                                            const float* __restrict__ pwv,
                                            float* __restrict__ out) {
  int gi = blockIdx.x * 256 + threadIdx.x;
  float s = 0.f, c = 0.f;
#pragma unroll
  for (int ch = 0; ch < NCH; ++ch) {
    s += part[(size_t)ch * NOUT + gi];
    c += corrp[(size_t)ch * NOUT + gi];
  }
  out[gi] = s / (pwv[P] - c + 1e-6f);
}

// ---- emergency fallback (no workspace needed) ----
__global__ __launch_bounds__(256) void kmono(const float* __restrict__ enroll,
                                             const float* __restrict__ test,
                                             const float* __restrict__ pho_w,
                                             const float* __restrict__ fc1w,
                                             const float* __restrict__ fc1b,
                                             const float* __restrict__ fc2w,
                                             float* __restrict__ out) {
  __shared__ float w1[C], b1[C], w2[C], pwm[P];
  const int t = threadIdx.x;
  if (t < C) {
    w1[t] = fc1w[t];
    b1[t] = fc1b[t];
    w2[t] = fc2w[t];
  }
  if (t < P) {
    float wmin = pho_w[0], wmax = pho_w[0];
    for (int i = 1; i < P; ++i) {
      float v = pho_w[i];
      wmin = fminf(wmin, v);
      wmax = fmaxf(wmax, v);
    }
    pwm[t] = (pho_w[t] - wmin) / (1e-6f + wmax - wmin);
  }
  __syncthreads();
  const int idx = blockIdx.x * 256 + t;
  const int a = idx >> 8, b = idx & 255;
  float score = 0.f, nz = 0.f;
  for (int p = 0; p < P; ++p) {
    float se = 0.f, st = 0.f, dot = 0.f;
    for (int d = 0; d < D; ++d) {
      float ev = enroll[((size_t)a * D + d) * P + p];
      float tv = test[((size_t)b * D + d) * P + p];
      se = fmaf(ev, ev, se);
      st = fmaf(tv, tv, st);
      dot = fmaf(ev, tv, dot);
    }
    float s = dot * (1.0f / fmaxf(sqrtf(se), 1e-12f)) * (1.0f / fmaxf(sqrtf(st), 1e-12f));
    float g = 0.f;
#pragma unroll
    for (int c = 0; c < C; ++c) g = fmaf(tanh_fast(fmaf(s, w1[c], b1[c])), w2[c], g);
    float f = tanh_fast(g * s);
    score = fmaf(f, pwm[p], score);
    if (s != 0.0f) nz += pwm[p];
  }
  out[idx] = score / (nz + 1e-6f);
}

}  // namespace

extern "C" void kernel_launch(void* const* d_in, const int* in_sizes, int n_in,
                              void* d_out, int out_size, void* d_ws, size_t ws_size,
                              hipStream_t stream) {
  const float* enroll = (const float*)d_in[0];
  const float* test = (const float*)d_in[1];
  const float* pho_w = (const float*)d_in[2];
  const float* fc1w = (const float*)d_in[3];
  const float* fc1b = (const float*)d_in[4];
  const float* fc2w = (const float*)d_in[5];
  float* out = (float*)d_out;

  const size_t sz_pair = (size_t)P * K * 256 * sizeof(unsigned);  // 10.49 MB each
  const size_t need = 2 * sz_pair + (size_t)2 * NCH * NOUT * sizeof(float) +
                      (size_t)(LN + 8) * sizeof(float) + (size_t)(P + 1) * sizeof(float);
  if (ws_size >= need) {
    unsigned* Ep = (unsigned*)d_ws;
    unsigned* Tp = Ep + sz_pair / 4;
    float* part = (float*)(Tp + sz_pair / 4);  // [8][NOUT]
    float* corrp = part + (size_t)NCH * NOUT;  // [8][NOUT]
    float* tab = corrp + (size_t)NCH * NOUT;
    float* pwv = tab + (LN + 4);

    kprep<<<2 * K + LB + 1, 256, 0, stream>>>(enroll, test, fc1w, fc1b, fc2w, pho_w,
                                              Ep, Tp, tab, pwv);
    kgemm<<<64 * NCH, 256, 0, stream>>>(Ep, Tp, tab, pwv, part, corrp);
    kdiv<<<NOUT / 256, 256, 0, stream>>>(part, corrp, pwv, out);
  } else {
    kmono<<<(K * K) / 256, 256, 0, stream>>>(enroll, test, pho_w, fc1w, fc1b, fc2w, out);
  }
}

// Round 13
// 35.410 us; speedup vs baseline: 1.0552x; 1.0552x over previous
//
#include <hip/hip_runtime.h>
#include <math.h>

namespace {

constexpr int K = 256, D = 256, P = 40, C = 32;
constexpr int LN = 2048;     // LUT intervals over s in [-1,1]
constexpr int NOUT = K * K;  // 65536
constexpr int LB = (LN + 1 + 255) / 256;  // LUT blocks
constexpr int CZB = 4;                    // corr-zero blocks (4 x 64 KB)

typedef __attribute__((ext_vector_type(8))) short bf16x8;
typedef __attribute__((ext_vector_type(4))) float f32x4;

__device__ __forceinline__ float tanh_fast(float x) {
  float e = __expf(2.0f * x);
  return 1.0f - __fdividef(2.0f, e + 1.0f);
}

// round-to-nearest bf16 split: (hi16) | (lo16 << 16); hi+lo ~ v to ~2^-18 rel
__device__ __forceinline__ unsigned bf16pair(float v) {
  unsigned u = __float_as_uint(v);
  unsigned hi = (u + 0x7fffu + ((u >> 16) & 1u)) >> 16;
  float lo = v - __uint_as_float(hi << 16);
  unsigned ul = __float_as_uint(lo);
  unsigned lo16 = (ul + 0x7fffu + ((ul >> 16) & 1u)) >> 16;
  return hi | (lo16 << 16);
}

__device__ __forceinline__ void gload16(const void* g, void* l) {
  __builtin_amdgcn_global_load_lds((const __attribute__((address_space(1))) void*)g,
                                   (__attribute__((address_space(3))) void*)l, 16, 0, 0);
}

// ---- prep (+ merged init): blocks [0,2K): L2-norm+transpose+bf16-split;
//      then LUT blocks; then corr-zero blocks; then pw block ----
__global__ __launch_bounds__(256) void kprep(const float* __restrict__ e,
                                             const float* __restrict__ ts,
                                             const float* __restrict__ fc1w,
                                             const float* __restrict__ fc1b,
                                             const float* __restrict__ fc2w,
                                             const float* __restrict__ pho_w,
                                             unsigned* __restrict__ Ep,
                                             unsigned* __restrict__ Tp,
                                             float* __restrict__ tab,
                                             float* __restrict__ corr,
                                             float* __restrict__ pwv) {
  const int bid = blockIdx.x;
  const int t = threadIdx.x;
  if (bid >= 2 * K) {
    int ib = bid - 2 * K;
    if (ib < LB) {
      int i = ib * 256 + t;
      if (i <= LN) {
        float s = -1.0f + (float)i * (2.0f / LN);
        float g = 0.f;
#pragma unroll
        for (int c = 0; c < C; ++c) g = fmaf(tanh_fast(fmaf(s, fc1w[c], fc1b[c])), fc2w[c], g);
        tab[i] = tanh_fast(g * s);
      }
      return;
    }
    ib -= LB;
    if (ib < CZB) {  // zero the 256 KB corr plane
      float4* cz = (float4*)corr + (size_t)ib * (256 * 16);
#pragma unroll
      for (int i = 0; i < 16; ++i) cz[i * 256 + t] = make_float4(0.f, 0.f, 0.f, 0.f);
      return;
    }
    // pw block: pwv[0..P) normalized weights, pwv[P] = sum
    float wmin = pho_w[0], wmax = pho_w[0];
    for (int i = 1; i < P; ++i) {
      float v = pho_w[i];
      wmin = fminf(wmin, v);
      wmax = fmaxf(wmax, v);
    }
    float inv = 1.0f / (1e-6f + wmax - wmin);
    if (t < P) pwv[t] = (pho_w[t] - wmin) * inv;
    if (t == 64) {
      float sum = 0.f;
      for (int i = 0; i < P; ++i) sum += (pho_w[i] - wmin) * inv;
      pwv[P] = sum;
    }
    return;
  }
  // ---- prep path ----
  __shared__ float tile[D * 41];  // padded stride 41
  __shared__ float red[240];
  __shared__ float inv[P];
  const float* x = (bid < K) ? e : ts;
  unsigned* xt = (bid < K) ? Ep : Tp;
  const int a = bid & (K - 1);
  const float4* src4 = (const float4*)(x + (size_t)a * D * P);
#pragma unroll
  for (int i4 = t; i4 < (D * P) / 4; i4 += 256) {
    float4 v = src4[i4];
    int d = i4 / 10;
    int p0 = (i4 - d * 10) * 4;
    float* dst = &tile[d * 41 + p0];
    dst[0] = v.x;
    dst[1] = v.y;
    dst[2] = v.z;
    dst[3] = v.w;
  }
  __syncthreads();
  if (t < 240) {  // 6 threads per column
    int p = t / 6, j = t - (t / 6) * 6;
    float ss = 0.f;
    for (int d = j; d < D; d += 6) {
      float v = tile[d * 41 + p];
      ss = fmaf(v, v, ss);
    }
    red[t] = ss;
  }
  __syncthreads();
  if (t < P) {
    float ss = red[t * 6] + red[t * 6 + 1] + red[t * 6 + 2] + red[t * 6 + 3] +
               red[t * 6 + 4] + red[t * 6 + 5];
    inv[t] = 1.0f / fmaxf(sqrtf(ss), 1e-12f);
  }
  __syncthreads();
  for (int i = t; i < (D * P) / 2; i += 256) {
    int p = i >> 7, d = (i & 127) * 2;
    float iv = inv[p];
    unsigned u0 = bf16pair(tile[d * 41 + p] * iv);
    unsigned u1 = bf16pair(tile[(d + 1) * 41 + p] * iv);
    *(uint2*)&xt[((size_t)p * K + a) * 256 + d] = make_uint2(u0, u1);
  }
}

// ---- kgemm: 640 blocks = 16 (64x64) tiles x 40 p; BK=128 double-buffered
//      (counted vmcnt(8)), 72 KB LDS -> 2 blocks/CU; non-atomic per-p planes ----
__global__ __launch_bounds__(256) void kgemm(const unsigned* __restrict__ Ep,
                                             const unsigned* __restrict__ Tp,
                                             const float* __restrict__ tab,
                                             const float* __restrict__ pwv,
                                             float* __restrict__ part,
                                             float* __restrict__ corr) {
  __shared__ __align__(16) char Buf[2][32 * 1024];  // [buf][A 16KB | B 16KB]
  __shared__ __align__(16) float lt[LN + 4];        // 8.2 KB LUT
  const int id = blockIdx.x;
  const int tile = id & 15;  // 4x4 tiles of 64x64
  const int p = id >> 4;
  const int a0 = (tile >> 2) * 64, b0 = (tile & 3) * 64;
  const int t = threadIdx.x, lane = t & 63, w = t >> 6;

  // staging: waves 0,1 -> A rows 0..63; waves 2,3 -> B rows 0..63 (rows of 256 B)
  const bool isB = (w >= 2);
  const char* panel = (isB ? (const char*)Tp : (const char*)Ep) + (size_t)p * (K * 1024) +
                      (size_t)(isB ? b0 : a0) * 1024;
  const int rbase0 = (w & 1) * 32;
  const int lrow = lane >> 4, l15s = lane & 15;
  const int dofs = isB ? 16 * 1024 : 0;

  auto stage = [&](char* buf, int ks) {
    char* dst = buf + dofs;
#pragma unroll
    for (int i = 0; i < 8; ++i) {
      const int R = rbase0 + i * 4;
      const int row = R + lrow;
      gload16(panel + (size_t)row * 1024 + ks * 256 + ((l15s * 16) ^ ((row & 7) << 4)),
              dst + R * 256);
    }
  };

  const float pwp = pwv[p];  // scalar load before the counted-vmcnt region

  stage(Buf[0], 0);  // prologue: 8 loads in flight per wave

  {  // LUT -> LDS (8 KB)
    const float4* t4 = (const float4*)tab;
    float4* l4 = (float4*)lt;
    l4[t] = t4[t];
    l4[t + 256] = t4[t + 256];
    if (t == 0) lt[LN] = tab[LN];
  }
  asm volatile("s_waitcnt vmcnt(0) lgkmcnt(0)" ::: "memory");
  __builtin_amdgcn_s_barrier();
  __builtin_amdgcn_sched_barrier(0);

  // compute geometry: wave w owns 32x32 quadrant (qr, qc); 2x2 frags of 16x16
  const int qr = (w >> 1) * 32, qc = (w & 1) * 32;
  const int l15 = lane & 15, hi16 = (lane >> 4) * 16;
  const int rsw = (l15 & 7) << 4;
  const char* Aq0 = nullptr;  // set per buffer below

  f32x4 acc00 = {0.f, 0.f, 0.f, 0.f}, acc01 = acc00, acc10 = acc00, acc11 = acc00;

#pragma unroll
  for (int ks = 0; ks < 4; ++ks) {
    const int cur = ks & 1;
    if (ks < 3) {
      stage(Buf[cur ^ 1], ks + 1);                      // 8 more in flight
      asm volatile("s_waitcnt vmcnt(8)" ::: "memory");  // current buf's 8 done
    } else {
      asm volatile("s_waitcnt vmcnt(0)" ::: "memory");
    }
    __builtin_amdgcn_s_barrier();
    __builtin_amdgcn_sched_barrier(0);
    const char* Ar0 = Buf[cur] + (size_t)(qr + l15) * 256;
    const char* Ar1 = Buf[cur] + (size_t)(qr + 16 + l15) * 256;
    const char* Br0 = Buf[cur] + 16 * 1024 + (size_t)(qc + l15) * 256;
    const char* Br1 = Buf[cur] + 16 * 1024 + (size_t)(qc + 16 + l15) * 256;
#pragma unroll
    for (int kk = 0; kk < 4; ++kk) {
      const int off = (kk * 64 + hi16) ^ rsw;
      bf16x8 af0 = *(const bf16x8*)(Ar0 + off);
      bf16x8 af1 = *(const bf16x8*)(Ar1 + off);
      bf16x8 bf0 = *(const bf16x8*)(Br0 + off);
      bf16x8 bf1 = *(const bf16x8*)(Br1 + off);
      acc00 = __builtin_amdgcn_mfma_f32_16x16x32_bf16(af0, bf0, acc00, 0, 0, 0);
      acc01 = __builtin_amdgcn_mfma_f32_16x16x32_bf16(af0, bf1, acc01, 0, 0, 0);
      acc10 = __builtin_amdgcn_mfma_f32_16x16x32_bf16(af1, bf0, acc10, 0, 0, 0);
      acc11 = __builtin_amdgcn_mfma_f32_16x16x32_bf16(af1, bf1, acc11, 0, 0, 0);
    }
    __builtin_amdgcn_s_barrier();  // reads of Buf[cur] done before it is re-staged
    __builtin_amdgcn_sched_barrier(0);
  }

  // epilogue: F(s) via LDS LUT, weighted, non-atomic write to this p's plane
  float* pp = part + (size_t)p * NOUT;
  const int ar = a0 + qr + (lane >> 4) * 4;
  const int bc = b0 + qc + l15;
#pragma unroll
  for (int j = 0; j < 4; ++j) {
    float sv[4] = {acc00[j], acc01[j], acc10[j], acc11[j]};
    int id4[4] = {(ar + j) * K + bc, (ar + j) * K + bc + 16,
                  (ar + 16 + j) * K + bc, (ar + 16 + j) * K + bc + 16};
#pragma unroll
    for (int q = 0; q < 4; ++q) {
      float s = sv[q];
      float u = fminf(fmaxf((s + 1.0f) * (LN / 2), 0.0f), (float)LN);
      int i = min((int)u, LN - 1);
      float F = fmaf(u - (float)i, lt[i + 1] - lt[i], lt[i]);
      pp[id4[q]] = F * pwp;
      if (s == 0.0f) atomicAdd(&corr[id4[q]], pwp);  // never taken on real data
    }
  }
}

// ---- finalize: reduce 40 p planes, divide ----
__global__ __launch_bounds__(256) void kdiv(const float* __restrict__ part,
                                            const float* __restrict__ corr,
                                            const float* __restrict__ pwv,
                                            float* __restrict__ out) {
  int gi = blockIdx.x * 256 + threadIdx.x;
  float s = 0.f;
#pragma unroll
  for (int p = 0; p < P; ++p) s += part[(size_t)p * NOUT + gi];
  out[gi] = s / (pwv[P] - corr[gi] + 1e-6f);
}

// ---- emergency fallback (no workspace needed) ----
__global__ __launch_bounds__(256) void kmono(const float* __restrict__ enroll,
                                             const float* __restrict__ test,
                                             const float* __restrict__ pho_w,
                                             const float* __restrict__ fc1w,
                                             const float* __restrict__ fc1b,
                                             const float* __restrict__ fc2w,
                                             float* __restrict__ out) {
  __shared__ float w1[C], b1[C], w2[C], pwm[P];
  const int t = threadIdx.x;
  if (t < C) {
    w1[t] = fc1w[t];
    b1[t] = fc1b[t];
    w2[t] = fc2w[t];
  }
  if (t < P) {
    float wmin = pho_w[0], wmax = pho_w[0];
    for (int i = 1; i < P; ++i) {
      float v = pho_w[i];
      wmin = fminf(wmin, v);
      wmax = fmaxf(wmax, v);
    }
    pwm[t] = (pho_w[t] - wmin) / (1e-6f + wmax - wmin);
  }
  __syncthreads();
  const int idx = blockIdx.x * 256 + t;
  const int a = idx >> 8, b = idx & 255;
  float score = 0.f, nz = 0.f;
  for (int p = 0; p < P; ++p) {
    float se = 0.f, st = 0.f, dot = 0.f;
    for (int d = 0; d < D; ++d) {
      float ev = enroll[((size_t)a * D + d) * P + p];
      float tv = test[((size_t)b * D + d) * P + p];
      se = fmaf(ev, ev, se);
      st = fmaf(tv, tv, st);
      dot = fmaf(ev, tv, dot);
    }
    float s = dot * (1.0f / fmaxf(sqrtf(se), 1e-12f)) * (1.0f / fmaxf(sqrtf(st), 1e-12f));
    float g = 0.f;
#pragma unroll
    for (int c = 0; c < C; ++c) g = fmaf(tanh_fast(fmaf(s, w1[c], b1[c])), w2[c], g);
    float f = tanh_fast(g * s);
    score = fmaf(f, pwm[p], score);
    if (s != 0.0f) nz += pwm[p];
  }
  out[idx] = score / (nz + 1e-6f);
}

}  // namespace

extern "C" void kernel_launch(void* const* d_in, const int* in_sizes, int n_in,
                              void* d_out, int out_size, void* d_ws, size_t ws_size,
                              hipStream_t stream) {
  const float* enroll = (const float*)d_in[0];
  const float* test = (const float*)d_in[1];
  const float* pho_w = (const float*)d_in[2];
  const float* fc1w = (const float*)d_in[3];
  const float* fc1b = (const float*)d_in[4];
  const float* fc2w = (const float*)d_in[5];
  float* out = (float*)d_out;

  const size_t sz_pair = (size_t)P * K * 256 * sizeof(unsigned);  // 10.49 MB each
  const size_t need = 2 * sz_pair + (size_t)P * NOUT * sizeof(float) +
                      (size_t)NOUT * sizeof(float) + (size_t)(LN + 8) * sizeof(float) +
                      (size_t)(P + 1) * sizeof(float);
  if (ws_size >= need) {
    unsigned* Ep = (unsigned*)d_ws;
    unsigned* Tp = Ep + sz_pair / 4;
    float* part = (float*)(Tp + sz_pair / 4);  // [40][NOUT]
    float* corr = part + (size_t)P * NOUT;     // [NOUT]
    float* tab = corr + NOUT;
    float* pwv = tab + (LN + 4);

    kprep<<<2 * K + LB + CZB + 1, 256, 0, stream>>>(enroll, test, fc1w, fc1b, fc2w, pho_w,
                                                    Ep, Tp, tab, corr, pwv);
    kgemm<<<16 * P, 256, 0, stream>>>(Ep, Tp, tab, pwv, part, corr);
    kdiv<<<NOUT / 256, 256, 0, stream>>>(part, corr, pwv, out);
  } else {
    kmono<<<(K * K) / 256, 256, 0, stream>>>(enroll, test, pho_w, fc1w, fc1b, fc2w, out);
  }
}

// Round 14
// 35.059 us; speedup vs baseline: 1.0658x; 1.0100x over previous
//
#include <hip/hip_runtime.h>
#include <math.h>

namespace {

constexpr int K = 256, D = 256, P = 40, C = 32;
constexpr int LN = 2048;     // LUT intervals over s in [-1,1]
constexpr int NOUT = K * K;  // 65536
constexpr int LB = (LN + 1 + 255) / 256;  // LUT blocks
constexpr int CZB = 4;                    // corr-zero blocks (4 x 64 KB)

typedef __attribute__((ext_vector_type(8))) short bf16x8;
typedef __attribute__((ext_vector_type(4))) float f32x4;

__device__ __forceinline__ float tanh_fast(float x) {
  float e = __expf(2.0f * x);
  return 1.0f - __fdividef(2.0f, e + 1.0f);
}

// round-to-nearest bf16 split: (hi16) | (lo16 << 16); hi+lo ~ v to ~2^-18 rel
__device__ __forceinline__ unsigned bf16pair(float v) {
  unsigned u = __float_as_uint(v);
  unsigned hi = (u + 0x7fffu + ((u >> 16) & 1u)) >> 16;
  float lo = v - __uint_as_float(hi << 16);
  unsigned ul = __float_as_uint(lo);
  unsigned lo16 = (ul + 0x7fffu + ((ul >> 16) & 1u)) >> 16;
  return hi | (lo16 << 16);
}

__device__ __forceinline__ void gload16(const void* g, void* l) {
  __builtin_amdgcn_global_load_lds((const __attribute__((address_space(1))) void*)g,
                                   (__attribute__((address_space(3))) void*)l, 16, 0, 0);
}

// ---- prep (+ merged init): blocks [0,2K): L2-norm+transpose+bf16-split;
//      then LUT blocks; then corr-zero blocks; then pw block ----
__global__ __launch_bounds__(256) void kprep(const float* __restrict__ e,
                                             const float* __restrict__ ts,
                                             const float* __restrict__ fc1w,
                                             const float* __restrict__ fc1b,
                                             const float* __restrict__ fc2w,
                                             const float* __restrict__ pho_w,
                                             unsigned* __restrict__ Ep,
                                             unsigned* __restrict__ Tp,
                                             float* __restrict__ tab,
                                             float* __restrict__ corr,
                                             float* __restrict__ pwv) {
  const int bid = blockIdx.x;
  const int t = threadIdx.x;
  if (bid >= 2 * K) {
    int ib = bid - 2 * K;
    if (ib < LB) {
      int i = ib * 256 + t;
      if (i <= LN) {
        float s = -1.0f + (float)i * (2.0f / LN);
        float g = 0.f;
#pragma unroll
        for (int c = 0; c < C; ++c) g = fmaf(tanh_fast(fmaf(s, fc1w[c], fc1b[c])), fc2w[c], g);
        tab[i] = tanh_fast(g * s);
      }
      return;
    }
    ib -= LB;
    if (ib < CZB) {  // zero the 256 KB corr plane
      float4* cz = (float4*)corr + (size_t)ib * (256 * 16);
#pragma unroll
      for (int i = 0; i < 16; ++i) cz[i * 256 + t] = make_float4(0.f, 0.f, 0.f, 0.f);
      return;
    }
    // pw block: pwv[0..P) normalized weights, pwv[P] = sum
    float wmin = pho_w[0], wmax = pho_w[0];
    for (int i = 1; i < P; ++i) {
      float v = pho_w[i];
      wmin = fminf(wmin, v);
      wmax = fmaxf(wmax, v);
    }
    float inv = 1.0f / (1e-6f + wmax - wmin);
    if (t < P) pwv[t] = (pho_w[t] - wmin) * inv;
    if (t == 64) {
      float sum = 0.f;
      for (int i = 0; i < P; ++i) sum += (pho_w[i] - wmin) * inv;
      pwv[P] = sum;
    }
    return;
  }
  // ---- prep path ----
  __shared__ float tile[D * 41];  // padded stride 41
  __shared__ float red[240];
  __shared__ float inv[P];
  const float* x = (bid < K) ? e : ts;
  unsigned* xt = (bid < K) ? Ep : Tp;
  const int a = bid & (K - 1);
  const float4* src4 = (const float4*)(x + (size_t)a * D * P);
#pragma unroll
  for (int i4 = t; i4 < (D * P) / 4; i4 += 256) {
    float4 v = src4[i4];
    int d = i4 / 10;
    int p0 = (i4 - d * 10) * 4;
    float* dst = &tile[d * 41 + p0];
    dst[0] = v.x;
    dst[1] = v.y;
    dst[2] = v.z;
    dst[3] = v.w;
  }
  __syncthreads();
  if (t < 240) {  // 6 threads per column
    int p = t / 6, j = t - (t / 6) * 6;
    float ss = 0.f;
    for (int d = j; d < D; d += 6) {
      float v = tile[d * 41 + p];
      ss = fmaf(v, v, ss);
    }
    red[t] = ss;
  }
  __syncthreads();
  if (t < P) {
    float ss = red[t * 6] + red[t * 6 + 1] + red[t * 6 + 2] + red[t * 6 + 3] +
               red[t * 6 + 4] + red[t * 6 + 5];
    inv[t] = 1.0f / fmaxf(sqrtf(ss), 1e-12f);
  }
  __syncthreads();
  for (int i = t; i < (D * P) / 2; i += 256) {
    int p = i >> 7, d = (i & 127) * 2;
    float iv = inv[p];
    unsigned u0 = bf16pair(tile[d * 41 + p] * iv);
    unsigned u1 = bf16pair(tile[(d + 1) * 41 + p] * iv);
    *(uint2*)&xt[((size_t)p * K + a) * 256 + d] = make_uint2(u0, u1);
  }
}

// ---- kgemm: 640 blocks = 16 (64x64) tiles x 40 p; BK=64 double-buffered
//      (counted vmcnt(4)), 32 KB LDS -> 5 blocks/CU, whole grid co-resident ----
__global__ __launch_bounds__(256) void kgemm(const unsigned* __restrict__ Ep,
                                             const unsigned* __restrict__ Tp,
                                             const float* __restrict__ tab,
                                             const float* __restrict__ pwv,
                                             float* __restrict__ part,
                                             float* __restrict__ corr) {
  __shared__ __align__(16) char Buf[2][16 * 1024];  // [buf][A 8KB | B 8KB]
  const int id = blockIdx.x;
  const int tile = id & 15;  // 4x4 tiles of 64x64
  const int p = id >> 4;
  const int a0 = (tile >> 2) * 64, b0 = (tile & 3) * 64;
  const int t = threadIdx.x, lane = t & 63, w = t >> 6;

  // staging: waves 0,1 -> A rows 0..63; waves 2,3 -> B rows 0..63 (rows of 128 B/step)
  const bool isB = (w >= 2);
  const char* panel = (isB ? (const char*)Tp : (const char*)Ep) + (size_t)p * (K * 1024) +
                      (size_t)(isB ? b0 : a0) * 1024;
  const int wrow0 = (w & 1) * 32;
  const int lrow = lane >> 3, lcol = (lane & 7) << 4;
  const int dofs = isB ? 8 * 1024 : 0;

  auto stage = [&](char* buf, int ks) {
    char* dst = buf + dofs;
#pragma unroll
    for (int i = 0; i < 4; ++i) {
      const int row = wrow0 + i * 8 + lrow;
      gload16(panel + (size_t)row * 1024 + ks * 128 + (lcol ^ ((row & 7) << 4)),
              dst + row * 128 + lcol);
    }
  };

  const float pwp = pwv[p];  // uniform s_load, no vmcnt traffic

  stage(Buf[0], 0);  // prologue: 4 loads in flight per wave

  // compute geometry: wave w owns 32x32 quadrant (qr, qc); 2x2 frags of 16x16
  const int qr = (w >> 1) * 32, qc = (w & 1) * 32;
  const int l15 = lane & 15, hi16 = (lane >> 4) * 16;
  const int rsw = (l15 & 7) << 4;

  f32x4 acc00 = {0.f, 0.f, 0.f, 0.f}, acc01 = acc00, acc10 = acc00, acc11 = acc00;

#pragma unroll
  for (int ks = 0; ks < 8; ++ks) {
    const int cur = ks & 1;
    if (ks < 7) {
      stage(Buf[cur ^ 1], ks + 1);                      // 4 more in flight
      asm volatile("s_waitcnt vmcnt(4)" ::: "memory");  // current buf's 4 done
    } else {
      asm volatile("s_waitcnt vmcnt(0)" ::: "memory");
    }
    __builtin_amdgcn_s_barrier();
    __builtin_amdgcn_sched_barrier(0);
    const char* Ar0 = Buf[cur] + (size_t)(qr + l15) * 128;
    const char* Ar1 = Buf[cur] + (size_t)(qr + 16 + l15) * 128;
    const char* Br0 = Buf[cur] + 8 * 1024 + (size_t)(qc + l15) * 128;
    const char* Br1 = Buf[cur] + 8 * 1024 + (size_t)(qc + 16 + l15) * 128;
    __builtin_amdgcn_s_setprio(1);
#pragma unroll
    for (int kk = 0; kk < 2; ++kk) {
      const int off = (kk * 64 + hi16) ^ rsw;
      bf16x8 af0 = *(const bf16x8*)(Ar0 + off);
      bf16x8 af1 = *(const bf16x8*)(Ar1 + off);
      bf16x8 bf0 = *(const bf16x8*)(Br0 + off);
      bf16x8 bf1 = *(const bf16x8*)(Br1 + off);
      acc00 = __builtin_amdgcn_mfma_f32_16x16x32_bf16(af0, bf0, acc00, 0, 0, 0);
      acc01 = __builtin_amdgcn_mfma_f32_16x16x32_bf16(af0, bf1, acc01, 0, 0, 0);
      acc10 = __builtin_amdgcn_mfma_f32_16x16x32_bf16(af1, bf0, acc10, 0, 0, 0);
      acc11 = __builtin_amdgcn_mfma_f32_16x16x32_bf16(af1, bf1, acc11, 0, 0, 0);
    }
    __builtin_amdgcn_s_setprio(0);
    __builtin_amdgcn_s_barrier();  // reads of Buf[cur] done before it is re-staged
    __builtin_amdgcn_sched_barrier(0);
  }

  // epilogue: F(s) via L2 LUT (8 KB, hot), weighted, non-atomic write to p's plane
  float* pp = part + (size_t)p * NOUT;
  const int ar = a0 + qr + (lane >> 4) * 4;
  const int bc = b0 + qc + l15;
#pragma unroll
  for (int j = 0; j < 4; ++j) {
    float sv[4] = {acc00[j], acc01[j], acc10[j], acc11[j]};
    int id4[4] = {(ar + j) * K + bc, (ar + j) * K + bc + 16,
                  (ar + 16 + j) * K + bc, (ar + 16 + j) * K + bc + 16};
#pragma unroll
    for (int q = 0; q < 4; ++q) {
      float s = sv[q];
      float u = fminf(fmaxf((s + 1.0f) * (LN / 2), 0.0f), (float)LN);
      int i = min((int)u, LN - 1);
      float lt0 = tab[i], lt1 = tab[i + 1];
      float F = fmaf(u - (float)i, lt1 - lt0, lt0);
      pp[id4[q]] = F * pwp;
      if (s == 0.0f) atomicAdd(&corr[id4[q]], pwp);  // never taken on real data
    }
  }
}

// ---- finalize: reduce 40 p planes, divide ----
__global__ __launch_bounds__(256) void kdiv(const float* __restrict__ part,
                                            const float* __restrict__ corr,
                                            const float* __restrict__ pwv,
                                            float* __restrict__ out) {
  int gi = blockIdx.x * 256 + threadIdx.x;
  float s = 0.f;
#pragma unroll
  for (int p = 0; p < P; ++p) s += part[(size_t)p * NOUT + gi];
  out[gi] = s / (pwv[P] - corr[gi] + 1e-6f);
}

// ---- emergency fallback (no workspace needed) ----
__global__ __launch_bounds__(256) void kmono(const float* __restrict__ enroll,
                                             const float* __restrict__ test,
                                             const float* __restrict__ pho_w,
                                             const float* __restrict__ fc1w,
                                             const float* __restrict__ fc1b,
                                             const float* __restrict__ fc2w,
                                             float* __restrict__ out) {
  __shared__ float w1[C], b1[C], w2[C], pwm[P];
  const int t = threadIdx.x;
  if (t < C) {
    w1[t] = fc1w[t];
    b1[t] = fc1b[t];
    w2[t] = fc2w[t];
  }
  if (t < P) {
    float wmin = pho_w[0], wmax = pho_w[0];
    for (int i = 1; i < P; ++i) {
      float v = pho_w[i];
      wmin = fminf(wmin, v);
      wmax = fmaxf(wmax, v);
    }
    pwm[t] = (pho_w[t] - wmin) / (1e-6f + wmax - wmin);
  }
  __syncthreads();
  const int idx = blockIdx.x * 256 + t;
  const int a = idx >> 8, b = idx & 255;
  float score = 0.f, nz = 0.f;
  for (int p = 0; p < P; ++p) {
    float se = 0.f, st = 0.f, dot = 0.f;
    for (int d = 0; d < D; ++d) {
      float ev = enroll[((size_t)a * D + d) * P + p];
      float tv = test[((size_t)b * D + d) * P + p];
      se = fmaf(ev, ev, se);
      st = fmaf(tv, tv, st);
      dot = fmaf(ev, tv, dot);
    }
    float s = dot * (1.0f / fmaxf(sqrtf(se), 1e-12f)) * (1.0f / fmaxf(sqrtf(st), 1e-12f));
    float g = 0.f;
#pragma unroll
    for (int c = 0; c < C; ++c) g = fmaf(tanh_fast(fmaf(s, w1[c], b1[c])), w2[c], g);
    float f = tanh_fast(g * s);
    score = fmaf(f, pwm[p], score);
    if (s != 0.0f) nz += pwm[p];
  }
  out[idx] = score / (nz + 1e-6f);
}

}  // namespace

extern "C" void kernel_launch(void* const* d_in, const int* in_sizes, int n_in,
                              void* d_out, int out_size, void* d_ws, size_t ws_size,
                              hipStream_t stream) {
  const float* enroll = (const float*)d_in[0];
  const float* test = (const float*)d_in[1];
  const float* pho_w = (const float*)d_in[2];
  const float* fc1w = (const float*)d_in[3];
  const float* fc1b = (const float*)d_in[4];
  const float* fc2w = (const float*)d_in[5];
  float* out = (float*)d_out;

  const size_t sz_pair = (size_t)P * K * 256 * sizeof(unsigned);  // 10.49 MB each
  const size_t need = 2 * sz_pair + (size_t)P * NOUT * sizeof(float) +
                      (size_t)NOUT * sizeof(float) + (size_t)(LN + 8) * sizeof(float) +
                      (size_t)(P + 1) * sizeof(float);
  if (ws_size >= need) {
    unsigned* Ep = (unsigned*)d_ws;
    unsigned* Tp = Ep + sz_pair / 4;
    float* part = (float*)(Tp + sz_pair / 4);  // [40][NOUT]
    float* corr = part + (size_t)P * NOUT;     // [NOUT]
    float* tab = corr + NOUT;
    float* pwv = tab + (LN + 4);

    kprep<<<2 * K + LB + CZB + 1, 256, 0, stream>>>(enroll, test, fc1w, fc1b, fc2w, pho_w,
                                                    Ep, Tp, tab, corr, pwv);
    kgemm<<<16 * P, 256, 0, stream>>>(Ep, Tp, tab, pwv, part, corr);
    kdiv<<<NOUT / 256, 256, 0, stream>>>(part, corr, pwv, out);
  } else {
    kmono<<<(K * K) / 256, 256, 0, stream>>>(enroll, test, pho_w, fc1w, fc1b, fc2w, out);
  }
}